// Round 1
// baseline (6203.165 us; speedup 1.0000x reference)
//
#include <hip/hip_runtime.h>
#include <hip/hip_bf16.h>
#include <stdint.h>
#include <stddef.h>

#define T_LEN 512
#define B_SZ  256
#define I_SZ  256
#define H_SZ  1024

typedef __attribute__((ext_vector_type(8))) short bf16x8;
typedef __attribute__((ext_vector_type(4))) float f32x4;
typedef unsigned short u16;
typedef unsigned int   u32;

__device__ inline u16 f2bf(float f) {
  union { float f; u32 u; } x; x.f = f;
  u32 r = x.u + 0x7fffu + ((x.u >> 16) & 1u);
  return (u16)(r >> 16);
}

// async global->LDS, 16B per lane; LDS dest must be wave-uniform-base + lane*16 (linear)
#define GLDS16(gp, lp) __builtin_amdgcn_global_load_lds( \
    (const __attribute__((address_space(1))) u32*)(gp),  \
    (__attribute__((address_space(3))) u32*)(lp), 16, 0, 0)

__global__ __launch_bounds__(256) void cvt_kernel(const float* __restrict__ src,
                                                  u16* __restrict__ dst, int n) {
  int stride = gridDim.x * blockDim.x * 4;
  for (int i = (blockIdx.x * blockDim.x + threadIdx.x) * 4; i < n; i += stride) {
    float4 v = *reinterpret_cast<const float4*>(src + i);
    ushort4 o;
    o.x = f2bf(v.x); o.y = f2bf(v.y); o.z = f2bf(v.z); o.w = f2bf(v.w);
    *reinterpret_cast<ushort4*>(dst + i) = o;
  }
}

// Stage 1: C[m,n] = sum_k A[m,k]*B[n,k] + b_in[n]; A=[131072,256] bf16, B=[1024,256] bf16 (B^T form)
// 128x128 tile, BK=32, 256 thr = 4 waves in 2x2, wave = 64x64 (4x4 frags of 16x16x32)
__global__ __launch_bounds__(256) void stage1_gemm(const u16* __restrict__ A,
                                                   const u16* __restrict__ Bw,
                                                   const float* __restrict__ b_in,
                                                   float* __restrict__ C) {
  __shared__ __align__(16) u16 As[128 * 32];
  __shared__ __align__(16) u16 Bs[128 * 32];
  const int tid  = threadIdx.x;
  const int lane = tid & 63;
  const int wid  = tid >> 6;
  const int wr   = wid >> 1, wc = wid & 1;
  const int bm0  = blockIdx.x * 128;
  const int bn0  = blockIdx.y * 128;
  const int rl   = lane & 15;
  const int kl   = (lane >> 4) * 8;

  f32x4 acc[4][4];
  for (int mi = 0; mi < 4; ++mi)
    for (int ni = 0; ni < 4; ++ni)
      acc[mi][ni] = (f32x4){0.f, 0.f, 0.f, 0.f};

  for (int kt = 0; kt < I_SZ / 32; ++kt) {
    const int k0 = kt * 32;
    __syncthreads();
    for (int t2 = 0; t2 < 2; ++t2) {
      int c = t2 * 256 + tid;
      int row = c >> 2, c8 = c & 3;
      GLDS16(A  + (size_t)(bm0 + row) * I_SZ + k0 + c8 * 8, As + c * 8);
      GLDS16(Bw + (size_t)(bn0 + row) * I_SZ + k0 + c8 * 8, Bs + c * 8);
    }
    __syncthreads();
    bf16x8 af[4], bfv[4];
    for (int mi = 0; mi < 4; ++mi)
      af[mi] = *reinterpret_cast<const bf16x8*>(&As[(wr * 64 + mi * 16 + rl) * 32 + kl]);
    for (int ni = 0; ni < 4; ++ni)
      bfv[ni] = *reinterpret_cast<const bf16x8*>(&Bs[(wc * 64 + ni * 16 + rl) * 32 + kl]);
    for (int mi = 0; mi < 4; ++mi)
      for (int ni = 0; ni < 4; ++ni)
        acc[mi][ni] = __builtin_amdgcn_mfma_f32_16x16x32_bf16(af[mi], bfv[ni], acc[mi][ni], 0, 0, 0);
  }

  const int rh = (lane >> 4) * 4;
  for (int ni = 0; ni < 4; ++ni) {
    int col = bn0 + wc * 64 + ni * 16 + rl;
    float bi = b_in[col];
    for (int mi = 0; mi < 4; ++mi) {
      int row = bm0 + wr * 64 + mi * 16 + rh;
      f32x4 c = acc[mi][ni];
      for (int r = 0; r < 4; ++r)
        C[(size_t)(row + r) * H_SZ + col] = c[r] + bi;
    }
  }
}

// One recurrence step: h = 0.9*h_prev + 0.1*relu(u + h_prev@W^T + b_hh)
// M=256(batch) x N=1024(j), K=1024. 32x64 tile -> grid(8,16)=128 WGs.
// 256 thr = 4 waves, wave = 32x16 (2 M-frags), BK=64 (2 MFMA-K chunks)
__global__ __launch_bounds__(256) void step_kernel(const u16* __restrict__ hb_in,
                                                   const u16* __restrict__ Whh,
                                                   const float* __restrict__ b_hh,
                                                   const float* __restrict__ hprev,
                                                   float* __restrict__ u_t,
                                                   u16* __restrict__ hb_out,
                                                   float* __restrict__ final_dst,
                                                   int first) {
  __shared__ __align__(16) u16 As[32 * 64];
  __shared__ __align__(16) u16 Bs[64 * 64];
  const int tid  = threadIdx.x;
  const int lane = tid & 63;
  const int wc   = tid >> 6;  // wave id = N-split (4 waves x 16 cols)
  const int bm0  = blockIdx.x * 32;
  const int bn0  = blockIdx.y * 64;
  const int rl   = lane & 15;
  const int kl   = (lane >> 4) * 8;
  const int rh   = (lane >> 4) * 4;

  f32x4 acc[2];
  acc[0] = (f32x4){0.f, 0.f, 0.f, 0.f};
  acc[1] = (f32x4){0.f, 0.f, 0.f, 0.f};

  for (int kt = 0; kt < H_SZ / 64; ++kt) {
    const int k0 = kt * 64;
    __syncthreads();
    {
      int row = tid >> 3, c8 = tid & 7;  // A: 32 rows x 64 cols = 256 chunks
      GLDS16(hb_in + (size_t)(bm0 + row) * H_SZ + k0 + c8 * 8, As + tid * 8);
      for (int t2 = 0; t2 < 2; ++t2) {   // B: 64 rows x 64 cols = 512 chunks
        int c = t2 * 256 + tid;
        int br = c >> 3, bc8 = c & 7;
        GLDS16(Whh + (size_t)(bn0 + br) * H_SZ + k0 + bc8 * 8, Bs + c * 8);
      }
    }
    __syncthreads();
    for (int kk = 0; kk < 2; ++kk) {
      bf16x8 b = *reinterpret_cast<const bf16x8*>(&Bs[(wc * 16 + rl) * 64 + kk * 32 + kl]);
      for (int mi = 0; mi < 2; ++mi) {
        bf16x8 a = *reinterpret_cast<const bf16x8*>(&As[(mi * 16 + rl) * 64 + kk * 32 + kl]);
        acc[mi] = __builtin_amdgcn_mfma_f32_16x16x32_bf16(a, b, acc[mi], 0, 0, 0);
      }
    }
  }

  const int col = bn0 + wc * 16 + rl;
  const float bh = b_hh[col];
  for (int mi = 0; mi < 2; ++mi) {
    int row = bm0 + mi * 16 + rh;
    f32x4 c = acc[mi];
    for (int r = 0; r < 4; ++r) {
      size_t idx = (size_t)(row + r) * H_SZ + col;
      float pre = u_t[idx] + c[r] + bh;
      float hn  = fmaxf(pre, 0.f);
      float hp  = first ? 0.f : hprev[idx];
      float h   = hp * 0.9f + hn * 0.1f;
      u_t[idx] = h;                 // overwrite u_t with h_t (fp32 output)
      hb_out[idx] = f2bf(h);        // bf16 copy for next step's A operand
      if (final_dst) final_dst[idx] = h;
    }
  }
}

extern "C" void kernel_launch(void* const* d_in, const int* in_sizes, int n_in,
                              void* d_out, int out_size, void* d_ws, size_t ws_size,
                              hipStream_t stream) {
  const float* x    = (const float*)d_in[0];
  const float* W_in = (const float*)d_in[1];
  const float* b_in = (const float*)d_in[2];
  const float* W_hh = (const float*)d_in[3];
  const float* b_hh = (const float*)d_in[4];
  float* out = (float*)d_out;

  // workspace layout (bytes)
  const size_t off_xb  = 0;                       // 512*256*256 bf16 = 67108864
  const size_t off_wib = 67108864;                // 1024*256  bf16 = 524288
  const size_t off_whb = 67633152;                // 1024*1024 bf16 = 2097152
  const size_t off_hb0 = 69730304;                // 256*1024  bf16 = 524288
  const size_t off_hb1 = 70254592;
  const size_t need    = 70778880;
  if (ws_size < need) return;  // fail loudly via wrong output rather than corrupt

  char* ws = (char*)d_ws;
  u16* xb  = (u16*)(ws + off_xb);
  u16* wib = (u16*)(ws + off_wib);
  u16* whb = (u16*)(ws + off_whb);
  u16* hb0 = (u16*)(ws + off_hb0);
  u16* hb1 = (u16*)(ws + off_hb1);

  cvt_kernel<<<1024, 256, 0, stream>>>(x,    xb,  T_LEN * B_SZ * I_SZ);
  cvt_kernel<<<64,   256, 0, stream>>>(W_in, wib, H_SZ * I_SZ);
  cvt_kernel<<<256,  256, 0, stream>>>(W_hh, whb, H_SZ * H_SZ);
  hipMemsetAsync(hb0, 0, (size_t)B_SZ * H_SZ * sizeof(u16), stream);

  dim3 g1(T_LEN * B_SZ / 128, H_SZ / 128);  // (1024, 8)
  stage1_gemm<<<g1, 256, 0, stream>>>(xb, wib, b_in, out);

  for (int t = 0; t < T_LEN; ++t) {
    const u16* hin = (t & 1) ? hb1 : hb0;
    u16* hout      = (t & 1) ? hb0 : hb1;
    float* u_t = out + (size_t)t * B_SZ * H_SZ;
    const float* hprev = (t > 0) ? out + (size_t)(t - 1) * B_SZ * H_SZ : nullptr;
    float* fin = (t == T_LEN - 1) ? out + (size_t)T_LEN * B_SZ * H_SZ : nullptr;
    step_kernel<<<dim3(B_SZ / 32, H_SZ / 64), 256, 0, stream>>>(
        hin, whb, b_hh, hprev, u_t, hout, fin, t == 0 ? 1 : 0);
  }
}